// Round 1
// baseline (150.198 us; speedup 1.0000x reference)
//
#include <hip/hip_runtime.h>
#include <stdint.h>
#include <stddef.h>

// ---------------------------------------------------------------------------
// GraphSAGE supervised forward (B=1024, D=HID=128, fanout 25/10, classes 64)
// Sampling reproduces jax.random (threefry2x32, partitionable=True defaults).
// ---------------------------------------------------------------------------

__host__ __device__ inline void tf2x32(uint32_t k0, uint32_t k1,
                                       uint32_t x0, uint32_t x1,
                                       uint32_t &o0, uint32_t &o1)
{
    uint32_t ks2 = k0 ^ k1 ^ 0x1BD11BDAu;
    uint32_t v0 = x0 + k0, v1 = x1 + k1;
#define TFR(d) { v0 += v1; v1 = (v1 << (d)) | (v1 >> (32 - (d))); v1 ^= v0; }
    TFR(13) TFR(15) TFR(26) TFR(6)   v0 += k1;  v1 += ks2 + 1u;
    TFR(17) TFR(29) TFR(16) TFR(24)  v0 += ks2; v1 += k0 + 2u;
    TFR(13) TFR(15) TFR(26) TFR(6)   v0 += k0;  v1 += k1 + 3u;
    TFR(17) TFR(29) TFR(16) TFR(24)  v0 += k1;  v1 += ks2 + 4u;
    TFR(13) TFR(15) TFR(26) TFR(6)   v0 += ks2; v1 += k0 + 5u;
#undef TFR
    o0 = v0; o1 = v1;
}

// ids_out[j] = adj[src[j/FAN] * 128 + ((o1^o2)&127)] with counter (0, j)
template <int FAN>
__global__ void sample_kernel(const int* __restrict__ src, const int* __restrict__ adj,
                              uint32_t ka, uint32_t kb, int* __restrict__ out, int total)
{
    int j = blockIdx.x * blockDim.x + threadIdx.x;
    if (j >= total) return;
    uint32_t h, l;
    tf2x32(ka, kb, 0u, (uint32_t)j, h, l);
    uint32_t col = (h ^ l) & 127u;
    int s = src[j / FAN];
    out[j] = adj[(size_t)s * 128u + col];
}

// out[row][0:128] = mean over FAN gathered feats rows. One wave per row.
template <int FAN>
__global__ void mean_gather_kernel(const int* __restrict__ ids, const float* __restrict__ feats,
                                   float* __restrict__ out, int rows)
{
    int g = blockIdx.x * blockDim.x + threadIdx.x;
    int row = g >> 6, lane = g & 63;
    if (row >= rows) return;
    const int* ip = ids + (size_t)row * FAN;
    float ax = 0.f, ay = 0.f;
#pragma unroll
    for (int t = 0; t < FAN; ++t) {
        size_t id = (size_t)ip[t];
        float2 v = *((const float2*)(feats + id * 128) + lane);
        ax += v.x; ay += v.y;
    }
    const float s = 1.0f / (float)FAN;
    float2 r; r.x = ax * s; r.y = ay * s;
    *((float2*)(out + (size_t)row * 128) + lane) = r;
}

// m2[row][0:256] = mean over 25 contiguous h1_1 rows. One wave per row.
__global__ void mean25_256_kernel(const float* __restrict__ in, float* __restrict__ out, int rows)
{
    int g = blockIdx.x * blockDim.x + threadIdx.x;
    int row = g >> 6, lane = g & 63;
    if (row >= rows) return;
    float a0 = 0, a1 = 0, a2 = 0, a3 = 0;
#pragma unroll
    for (int t = 0; t < 25; ++t) {
        float4 v = *((const float4*)(in + ((size_t)row * 25 + t) * 256) + lane);
        a0 += v.x; a1 += v.y; a2 += v.z; a3 += v.w;
    }
    const float s = 1.0f / 25.0f;
    float4 r; r.x = a0 * s; r.y = a1 * s; r.z = a2 * s; r.w = a3 * s;
    *((float4*)(out + (size_t)row * 256) + lane) = r;
}

// C[r][ccol0 + cb + c] = (relu?) A_row(r) @ W[:, cb+c], A row optionally gathered.
// Tile 64x64, K-tile 64, 256 threads, each 4x4 outputs.
__launch_bounds__(256)
__global__ void gemm_tile_kernel(const float* __restrict__ Abase, const int* __restrict__ gids,
                                 int K, const float* __restrict__ W, int ldw,
                                 float* __restrict__ C, int ldc, int ccol0,
                                 int rows, int relu)
{
    __shared__ float As[64][68];
    __shared__ float Ws[64][68];
    const int tid = threadIdx.x;
    const int rb = blockIdx.x * 64;
    const int cb = blockIdx.y * 64;
    const int tx = tid & 15, ty = tid >> 4;
    float acc[4][4] = {};

    for (int k0 = 0; k0 < K; k0 += 64) {
#pragma unroll
        for (int i = 0; i < 4; ++i) {               // A tile: 64 rows x 64 k
            int idx = tid + i * 256;
            int r = idx >> 4, f = idx & 15;
            int gr = rb + r;
            float4 v = make_float4(0.f, 0.f, 0.f, 0.f);
            if (gr < rows) {
                size_t arow = gids ? (size_t)gids[gr] : (size_t)gr;
                v = *(const float4*)(Abase + arow * (size_t)K + k0 + f * 4);
            }
            *(float4*)&As[r][f * 4] = v;
        }
#pragma unroll
        for (int i = 0; i < 4; ++i) {               // W tile: 64 k x 64 cols
            int idx = tid + i * 256;
            int kk = idx >> 4, f = idx & 15;
            float4 v = *(const float4*)(W + (size_t)(k0 + kk) * ldw + cb + f * 4);
            *(float4*)&Ws[kk][f * 4] = v;
        }
        __syncthreads();
#pragma unroll
        for (int kk = 0; kk < 64; ++kk) {
            float b[4];
            *(float4*)b = *(const float4*)&Ws[kk][tx * 4];
            float a[4];
#pragma unroll
            for (int i = 0; i < 4; ++i) a[i] = As[ty * 4 + i][kk];
#pragma unroll
            for (int i = 0; i < 4; ++i)
#pragma unroll
                for (int j = 0; j < 4; ++j)
                    acc[i][j] = fmaf(a[i], b[j], acc[i][j]);
        }
        __syncthreads();
    }
#pragma unroll
    for (int i = 0; i < 4; ++i) {
        int r = rb + ty * 4 + i;
        if (r >= rows) continue;
#pragma unroll
        for (int j = 0; j < 4; ++j) {
            float v = acc[i][j];
            if (relu) v = fmaxf(v, 0.0f);
            C[(size_t)r * ldc + ccol0 + cb + tx * 4 + j] = v;
        }
    }
}

// out[row][c] = normalize(H[row]) @ fc_w[:,c] + fc_b[c]. One wave per row, lane=class.
__launch_bounds__(256)
__global__ void norm_fc_kernel(const float* __restrict__ H, const float* __restrict__ fcw,
                               const float* __restrict__ fcb, float* __restrict__ out, int rows)
{
    __shared__ float srow[4][256];
    int lane = threadIdx.x & 63;
    int w = threadIdx.x >> 6;
    int row = blockIdx.x * 4 + w;
    bool active = row < rows;

    float4 v = make_float4(0.f, 0.f, 0.f, 0.f);
    if (active) v = *((const float4*)(H + (size_t)row * 256) + lane);
    float ss = v.x * v.x + v.y * v.y + v.z * v.z + v.w * v.w;
#pragma unroll
    for (int o = 32; o > 0; o >>= 1) ss += __shfl_xor(ss, o, 64);
    float scale = 1.0f / fmaxf(sqrtf(ss), 1e-12f);
    float4 sv; sv.x = v.x * scale; sv.y = v.y * scale; sv.z = v.z * scale; sv.w = v.w * scale;
    *((float4*)&srow[w][0] + lane) = sv;
    __syncthreads();

    float acc = fcb[lane];
#pragma unroll 4
    for (int k = 0; k < 256; ++k)
        acc = fmaf(srow[w][k], fcw[(size_t)k * 64 + lane], acc);
    if (active) out[(size_t)row * 64 + lane] = acc;
}

extern "C" void kernel_launch(void* const* d_in, const int* in_sizes, int n_in,
                              void* d_out, int out_size, void* d_ws, size_t ws_size,
                              hipStream_t stream)
{
    const int*   ids   = (const int*)d_in[0];
    const float* feats = (const float*)d_in[1];
    const int*   adj   = (const int*)d_in[2];
    const float* W_x1  = (const float*)d_in[3];
    const float* W_n1  = (const float*)d_in[4];
    const float* W_x2  = (const float*)d_in[5];
    const float* W_n2  = (const float*)d_in[6];
    const float* fc_w  = (const float*)d_in[7];
    const float* fc_b  = (const float*)d_in[8];
    float* out = (float*)d_out;

    char* ws = (char*)d_ws;
    int*   ids1 = (int*)(ws + 0);            // 25600 ints
    int*   ids2 = (int*)(ws + 102400);       // 256000 ints
    float* m1   = (float*)(ws + 1126400);    // 25600 x 128 f32
    float* m0   = (float*)(ws + 14233600);   // 1024 x 128
    float* h11  = (float*)(ws + 14757888);   // 25600 x 256
    float* h10  = (float*)(ws + 40972288);   // 1024 x 256
    float* m2   = (float*)(ws + 42020864);   // 1024 x 256
    float* h2   = (float*)(ws + 43069440);   // 1024 x 256  (end: 44,118,016 B)

    // JAX PRNG key derivation on host (all compile-time constants really):
    // key = key(42) = (0,42); Ki = fold_in(key, i) = block(key,(0,i));
    // randint uses k2 = split(Ki)[1] = block(Ki,(0,1)) (partitionable foldlike).
    uint32_t f0a, f0b, f1a, f1b, s0a, s0b, s1a, s1b;
    tf2x32(0u, 42u, 0u, 0u, f0a, f0b);
    tf2x32(0u, 42u, 0u, 1u, f1a, f1b);
    tf2x32(f0a, f0b, 0u, 1u, s0a, s0b);
    tf2x32(f1a, f1b, 0u, 1u, s1a, s1b);

    // hop sampling
    sample_kernel<25><<<100, 256, 0, stream>>>(ids, adj, s0a, s0b, ids1, 25600);
    sample_kernel<10><<<1000, 256, 0, stream>>>(ids1, adj, s1a, s1b, ids2, 256000);

    // neighbor means of raw features
    mean_gather_kernel<10><<<6400, 256, 0, stream>>>(ids2, feats, m1, 25600);
    mean_gather_kernel<25><<<256, 256, 0, stream>>>(ids1, feats, m0, 1024);

    // layer 1 (relu): h = relu([x @ Wx1, agg @ Wn1])
    dim3 gL1(400, 2), gS(16, 2);
    gemm_tile_kernel<<<gL1, 256, 0, stream>>>(feats, ids1, 128, W_x1, 128, h11, 256, 0,   25600, 1);
    gemm_tile_kernel<<<gL1, 256, 0, stream>>>(m1,  nullptr, 128, W_n1, 128, h11, 256, 128, 25600, 1);
    gemm_tile_kernel<<<gS, 256, 0, stream>>>(feats, ids,   128, W_x1, 128, h10, 256, 0,   1024, 1);
    gemm_tile_kernel<<<gS, 256, 0, stream>>>(m0,  nullptr, 128, W_n1, 128, h10, 256, 128, 1024, 1);

    // layer 2 (no act): h2 = [h1_0 @ Wx2, mean25(h1_1) @ Wn2]
    mean25_256_kernel<<<256, 256, 0, stream>>>(h11, m2, 1024);
    gemm_tile_kernel<<<gS, 256, 0, stream>>>(h10, nullptr, 256, W_x2, 128, h2, 256, 0,   1024, 0);
    gemm_tile_kernel<<<gS, 256, 0, stream>>>(m2,  nullptr, 256, W_n2, 128, h2, 256, 128, 1024, 0);

    // normalize rows + FC
    norm_fc_kernel<<<256, 256, 0, stream>>>(h2, fc_w, fc_b, out, 1024);
}

// Round 2
// 104.902 us; speedup vs baseline: 1.4318x; 1.4318x over previous
//
#include <hip/hip_runtime.h>
#include <stdint.h>
#include <stddef.h>

// ---------------------------------------------------------------------------
// GraphSAGE supervised forward (B=1024, D=HID=128, fanout 25/10, classes 64)
// Round 2: launch fusion 12 -> 6 kernels; hop-2 sampling fused into gather.
// ---------------------------------------------------------------------------

__host__ __device__ inline void tf2x32(uint32_t k0, uint32_t k1,
                                       uint32_t x0, uint32_t x1,
                                       uint32_t &o0, uint32_t &o1)
{
    uint32_t ks2 = k0 ^ k1 ^ 0x1BD11BDAu;
    uint32_t v0 = x0 + k0, v1 = x1 + k1;
#define TFR(d) { v0 += v1; v1 = (v1 << (d)) | (v1 >> (32 - (d))); v1 ^= v0; }
    TFR(13) TFR(15) TFR(26) TFR(6)   v0 += k1;  v1 += ks2 + 1u;
    TFR(17) TFR(29) TFR(16) TFR(24)  v0 += ks2; v1 += k0 + 2u;
    TFR(13) TFR(15) TFR(26) TFR(6)   v0 += k0;  v1 += k1 + 3u;
    TFR(17) TFR(29) TFR(16) TFR(24)  v0 += k1;  v1 += ks2 + 4u;
    TFR(13) TFR(15) TFR(26) TFR(6)   v0 += ks2; v1 += k0 + 5u;
#undef TFR
    o0 = v0; o1 = v1;
}

// hop-1: ids1[j] = adj[ids[j/25]*128 + ((h^l)&127)], counter (0, j)
__global__ void sample25_kernel(const int* __restrict__ src, const int* __restrict__ adj,
                                uint32_t ka, uint32_t kb, int* __restrict__ out, int total)
{
    int j = blockIdx.x * blockDim.x + threadIdx.x;
    if (j >= total) return;
    uint32_t h, l;
    tf2x32(ka, kb, 0u, (uint32_t)j, h, l);
    int s = src[j / 25];
    out[j] = adj[(size_t)s * 128u + ((h ^ l) & 127u)];
}

// One wave per output row.
//   waves [0, 25600): hop-2 sample (in-wave threefry) + mean of 10 feats -> m1
//   waves [25600, 26624): mean of 25 feats rows per ids1 -> m0
__global__ void means_kernel(const int* __restrict__ ids1, const int* __restrict__ adj,
                             const float* __restrict__ feats, uint32_t ka, uint32_t kb,
                             float* __restrict__ m1, float* __restrict__ m0)
{
    int g = blockIdx.x * blockDim.x + threadIdx.x;
    int w = g >> 6, lane = g & 63;
    if (w < 25600) {
        int s = ids1[w];
        int idv = 0;
        if (lane < 10) {
            uint32_t h, l;
            tf2x32(ka, kb, 0u, (uint32_t)(w * 10 + lane), h, l);
            idv = adj[(size_t)s * 128u + ((h ^ l) & 127u)];
        }
        float ax = 0.f, ay = 0.f;
#pragma unroll
        for (int t = 0; t < 10; ++t) {
            int id = __shfl(idv, t, 64);
            float2 v = *((const float2*)(feats + (size_t)id * 128) + lane);
            ax += v.x; ay += v.y;
        }
        *((float2*)(m1 + (size_t)w * 128) + lane) = make_float2(ax * 0.1f, ay * 0.1f);
    } else if (w < 26624) {
        int row = w - 25600;
        const int* ip = ids1 + row * 25;
        float ax = 0.f, ay = 0.f;
#pragma unroll
        for (int t = 0; t < 25; ++t) {
            int id = ip[t];
            float2 v = *((const float2*)(feats + (size_t)id * 128) + lane);
            ax += v.x; ay += v.y;
        }
        const float s = 1.0f / 25.0f;
        *((float2*)(m0 + (size_t)row * 128) + lane) = make_float2(ax * s, ay * s);
    }
}

// m2[row][0:256] = mean over 25 contiguous h11 rows. One wave per row.
__global__ void mean25_256_kernel(const float* __restrict__ in, float* __restrict__ out, int rows)
{
    int g = blockIdx.x * blockDim.x + threadIdx.x;
    int row = g >> 6, lane = g & 63;
    if (row >= rows) return;
    float a0 = 0, a1 = 0, a2 = 0, a3 = 0;
#pragma unroll
    for (int t = 0; t < 25; ++t) {
        float4 v = *((const float4*)(in + ((size_t)row * 25 + t) * 256) + lane);
        a0 += v.x; a1 += v.y; a2 += v.z; a3 += v.w;
    }
    const float s = 1.0f / 25.0f;
    float4 r; r.x = a0 * s; r.y = a1 * s; r.z = a2 * s; r.w = a3 * s;
    *((float4*)(out + (size_t)row * 256) + lane) = r;
}

// Shared 64x64-tile f32 GEMM body (validated r1 inner loop, unchanged).
__device__ __forceinline__ void gemm_body(float (*As)[68], float (*Ws)[68],
    const float* __restrict__ A, const int* __restrict__ g, int K,
    const float* __restrict__ W, int ldw, float* __restrict__ C, int ldc,
    int ccol0, int rows, bool relu)
{
    const int tid = threadIdx.x;
    const int rb = blockIdx.x * 64;
    const int cb = blockIdx.y * 64;
    const int tx = tid & 15, ty = tid >> 4;
    float acc[4][4] = {};

    for (int k0 = 0; k0 < K; k0 += 64) {
#pragma unroll
        for (int i = 0; i < 4; ++i) {               // A tile: 64 rows x 64 k
            int idx = tid + i * 256;
            int r = idx >> 4, f = idx & 15;
            int gr = rb + r;
            float4 v = make_float4(0.f, 0.f, 0.f, 0.f);
            if (gr < rows) {
                size_t arow = g ? (size_t)g[gr] : (size_t)gr;
                v = *(const float4*)(A + arow * (size_t)K + k0 + f * 4);
            }
            *(float4*)&As[r][f * 4] = v;
        }
#pragma unroll
        for (int i = 0; i < 4; ++i) {               // W tile: 64 k x 64 cols
            int idx = tid + i * 256;
            int kk = idx >> 4, f = idx & 15;
            float4 v = *(const float4*)(W + (size_t)(k0 + kk) * ldw + cb + f * 4);
            *(float4*)&Ws[kk][f * 4] = v;
        }
        __syncthreads();
#pragma unroll
        for (int kk = 0; kk < 64; ++kk) {
            float b[4];
            *(float4*)b = *(const float4*)&Ws[kk][tx * 4];
            float a[4];
#pragma unroll
            for (int i = 0; i < 4; ++i) a[i] = As[ty * 4 + i][kk];
#pragma unroll
            for (int i = 0; i < 4; ++i)
#pragma unroll
                for (int j = 0; j < 4; ++j)
                    acc[i][j] = fmaf(a[i], b[j], acc[i][j]);
        }
        __syncthreads();
    }
#pragma unroll
    for (int i = 0; i < 4; ++i) {
        int r = rb + ty * 4 + i;
        if (r >= rows) continue;
#pragma unroll
        for (int j = 0; j < 4; ++j) {
            float v = acc[i][j];
            if (relu) v = fmaxf(v, 0.0f);
            C[(size_t)r * ldc + ccol0 + cb + tx * 4 + j] = v;
        }
    }
}

// Layer-1: all four matmuls in one launch, z selects {big-x, big-n, small-x, small-n}.
__launch_bounds__(256)
__global__ void gemm_l1_kernel(const float* __restrict__ feats,
                               const int* __restrict__ ids0, const int* __restrict__ ids1,
                               const float* __restrict__ m1, const float* __restrict__ m0,
                               const float* __restrict__ Wx1, const float* __restrict__ Wn1,
                               float* __restrict__ h11, float* __restrict__ h10)
{
    const float* A; const int* g; const float* W; float* C; int rows, ccol0;
    switch (blockIdx.z) {
    case 0:  A = feats; g = ids1;    W = Wx1; C = h11; rows = 25600; ccol0 = 0;   break;
    case 1:  A = m1;    g = nullptr; W = Wn1; C = h11; rows = 25600; ccol0 = 128; break;
    case 2:  A = feats; g = ids0;    W = Wx1; C = h10; rows = 1024;  ccol0 = 0;   break;
    default: A = m0;    g = nullptr; W = Wn1; C = h10; rows = 1024;  ccol0 = 128; break;
    }
    if ((int)blockIdx.x * 64 >= rows) return;
    __shared__ float As[64][68];
    __shared__ float Ws[64][68];
    gemm_body(As, Ws, A, g, 128, W, 128, C, 256, ccol0, rows, true);
}

// Layer-2: both matmuls in one launch.
__launch_bounds__(256)
__global__ void gemm_l2_kernel(const float* __restrict__ h10, const float* __restrict__ m2,
                               const float* __restrict__ Wx2, const float* __restrict__ Wn2,
                               float* __restrict__ h2)
{
    const float* A; const float* W; int ccol0;
    if (blockIdx.z == 0) { A = h10; W = Wx2; ccol0 = 0; }
    else                 { A = m2;  W = Wn2; ccol0 = 128; }
    __shared__ float As[64][68];
    __shared__ float Ws[64][68];
    gemm_body(As, Ws, A, nullptr, 256, W, 128, h2, 256, ccol0, 1024, false);
}

// out[row][c] = normalize(H[row]) @ fc_w[:,c] + fc_b[c]. One wave per row.
__launch_bounds__(256)
__global__ void norm_fc_kernel(const float* __restrict__ H, const float* __restrict__ fcw,
                               const float* __restrict__ fcb, float* __restrict__ out, int rows)
{
    __shared__ float srow[4][256];
    int lane = threadIdx.x & 63;
    int w = threadIdx.x >> 6;
    int row = blockIdx.x * 4 + w;
    bool active = row < rows;

    float4 v = make_float4(0.f, 0.f, 0.f, 0.f);
    if (active) v = *((const float4*)(H + (size_t)row * 256) + lane);
    float ss = v.x * v.x + v.y * v.y + v.z * v.z + v.w * v.w;
#pragma unroll
    for (int o = 32; o > 0; o >>= 1) ss += __shfl_xor(ss, o, 64);
    float scale = 1.0f / fmaxf(sqrtf(ss), 1e-12f);
    float4 sv; sv.x = v.x * scale; sv.y = v.y * scale; sv.z = v.z * scale; sv.w = v.w * scale;
    *((float4*)&srow[w][0] + lane) = sv;
    __syncthreads();

    float acc = fcb[lane];
#pragma unroll 4
    for (int k = 0; k < 256; ++k)
        acc = fmaf(srow[w][k], fcw[(size_t)k * 64 + lane], acc);
    if (active) out[(size_t)row * 64 + lane] = acc;
}

extern "C" void kernel_launch(void* const* d_in, const int* in_sizes, int n_in,
                              void* d_out, int out_size, void* d_ws, size_t ws_size,
                              hipStream_t stream)
{
    const int*   ids   = (const int*)d_in[0];
    const float* feats = (const float*)d_in[1];
    const int*   adj   = (const int*)d_in[2];
    const float* W_x1  = (const float*)d_in[3];
    const float* W_n1  = (const float*)d_in[4];
    const float* W_x2  = (const float*)d_in[5];
    const float* W_n2  = (const float*)d_in[6];
    const float* fc_w  = (const float*)d_in[7];
    const float* fc_b  = (const float*)d_in[8];
    float* out = (float*)d_out;

    char* ws = (char*)d_ws;
    int*   ids1 = (int*)(ws + 0);            // 25600 ints           (102,400 B)
    float* m1   = (float*)(ws + 102400);     // 25600 x 128 f32      (13,107,200 B)
    float* m0   = (float*)(ws + 13209600);   // 1024 x 128           (524,288 B)
    float* h11  = (float*)(ws + 13733888);   // 25600 x 256          (26,214,400 B)
    float* h10  = (float*)(ws + 39948288);   // 1024 x 256           (1,048,576 B)
    float* m2   = (float*)(ws + 40996864);   // 1024 x 256           (1,048,576 B)
    float* h2   = (float*)(ws + 42045440);   // 1024 x 256  (end 43,094,016 B)

    // JAX PRNG key derivation (threefry2x32, partitionable foldlike):
    // key(42)=(0,42); Ki=fold_in(key,i); randint key = split(Ki)[1] = block(Ki,(0,1)).
    uint32_t f0a, f0b, f1a, f1b, s0a, s0b, s1a, s1b;
    tf2x32(0u, 42u, 0u, 0u, f0a, f0b);
    tf2x32(0u, 42u, 0u, 1u, f1a, f1b);
    tf2x32(f0a, f0b, 0u, 1u, s0a, s0b);
    tf2x32(f1a, f1b, 0u, 1u, s1a, s1b);

    // 1) hop-1 sampling
    sample25_kernel<<<100, 256, 0, stream>>>(ids, adj, s0a, s0b, ids1, 25600);
    // 2) hop-2 sampling fused with feats means (m1), plus m0
    means_kernel<<<6656, 256, 0, stream>>>(ids1, adj, feats, s1a, s1b, m1, m0);
    // 3) layer 1: all four matmuls, relu
    gemm_l1_kernel<<<dim3(400, 2, 4), 256, 0, stream>>>(feats, ids, ids1, m1, m0,
                                                        W_x1, W_n1, h11, h10);
    // 4) mean over 25 h11 rows
    mean25_256_kernel<<<256, 256, 0, stream>>>(h11, m2, 1024);
    // 5) layer 2: both matmuls, no act
    gemm_l2_kernel<<<dim3(16, 2, 2), 256, 0, stream>>>(h10, m2, W_x2, W_n2, h2);
    // 6) normalize rows + FC
    norm_fc_kernel<<<256, 256, 0, stream>>>(h2, fc_w, fc_b, out, 1024);
}

// Round 3
// 94.850 us; speedup vs baseline: 1.5835x; 1.1060x over previous
//
#include <hip/hip_runtime.h>
#include <stdint.h>
#include <stddef.h>

// ---------------------------------------------------------------------------
// GraphSAGE supervised forward (B=1024, D=HID=128, fanout 25/10, classes 64)
// Round 3: layer-1 matmuls -> split-bf16 MFMA (AhiBhi + AhiBlo + AloBhi).
// ---------------------------------------------------------------------------

typedef short bf16x8v __attribute__((ext_vector_type(8)));   // 8 bf16 bit patterns
typedef float f32x4v __attribute__((ext_vector_type(4)));

__host__ __device__ inline void tf2x32(uint32_t k0, uint32_t k1,
                                       uint32_t x0, uint32_t x1,
                                       uint32_t &o0, uint32_t &o1)
{
    uint32_t ks2 = k0 ^ k1 ^ 0x1BD11BDAu;
    uint32_t v0 = x0 + k0, v1 = x1 + k1;
#define TFR(d) { v0 += v1; v1 = (v1 << (d)) | (v1 >> (32 - (d))); v1 ^= v0; }
    TFR(13) TFR(15) TFR(26) TFR(6)   v0 += k1;  v1 += ks2 + 1u;
    TFR(17) TFR(29) TFR(16) TFR(24)  v0 += ks2; v1 += k0 + 2u;
    TFR(13) TFR(15) TFR(26) TFR(6)   v0 += k0;  v1 += k1 + 3u;
    TFR(17) TFR(29) TFR(16) TFR(24)  v0 += k1;  v1 += ks2 + 4u;
    TFR(13) TFR(15) TFR(26) TFR(6)   v0 += ks2; v1 += k0 + 5u;
#undef TFR
    o0 = v0; o1 = v1;
}

__device__ inline uint16_t f32_to_bf16_rne(float f)
{
    uint32_t u = __float_as_uint(f);
    u += 0x7FFFu + ((u >> 16) & 1u);
    return (uint16_t)(u >> 16);
}
__device__ inline float bf16_to_f32(uint16_t h)
{
    return __uint_as_float(((uint32_t)h) << 16);
}

// hop-1: ids1[j] = adj[ids[j/25]*128 + ((h^l)&127)], counter (0, j)
__global__ void sample25_kernel(const int* __restrict__ src, const int* __restrict__ adj,
                                uint32_t ka, uint32_t kb, int* __restrict__ out, int total)
{
    int j = blockIdx.x * blockDim.x + threadIdx.x;
    if (j >= total) return;
    uint32_t h, l;
    tf2x32(ka, kb, 0u, (uint32_t)j, h, l);
    int s = src[j / 25];
    out[j] = adj[(size_t)s * 128u + ((h ^ l) & 127u)];
}

// W split prep: Wt_hi[n][k], Wt_lo[n][k] (bf16) from W[k][n] (f32 128x128).
__global__ void wprep_kernel(const float* __restrict__ Wx1, const float* __restrict__ Wn1,
                             uint16_t* __restrict__ xh, uint16_t* __restrict__ xl,
                             uint16_t* __restrict__ nh, uint16_t* __restrict__ nl)
{
    int idx = blockIdx.x * 256 + threadIdx.x;      // [0, 16384)
    int k = idx >> 7, n = idx & 127;
    const float* W = blockIdx.y ? Wn1 : Wx1;
    uint16_t* H = blockIdx.y ? nh : xh;
    uint16_t* L = blockIdx.y ? nl : xl;
    float v = W[k * 128 + n];
    uint16_t h = f32_to_bf16_rne(v);
    uint16_t l = f32_to_bf16_rne(v - bf16_to_f32(h));
    H[n * 128 + k] = h;
    L[n * 128 + k] = l;
}

// One wave per output row.
//   waves [0, 25600): hop-2 sample (in-wave threefry) + mean of 10 feats -> m1
//   waves [25600, 26624): mean of 25 feats rows per ids1 -> m0
__global__ void means_kernel(const int* __restrict__ ids1, const int* __restrict__ adj,
                             const float* __restrict__ feats, uint32_t ka, uint32_t kb,
                             float* __restrict__ m1, float* __restrict__ m0)
{
    int g = blockIdx.x * blockDim.x + threadIdx.x;
    int w = g >> 6, lane = g & 63;
    if (w < 25600) {
        int s = ids1[w];
        int idv = 0;
        if (lane < 10) {
            uint32_t h, l;
            tf2x32(ka, kb, 0u, (uint32_t)(w * 10 + lane), h, l);
            idv = adj[(size_t)s * 128u + ((h ^ l) & 127u)];
        }
        float ax = 0.f, ay = 0.f;
#pragma unroll
        for (int t = 0; t < 10; ++t) {
            int id = __shfl(idv, t, 64);
            float2 v = *((const float2*)(feats + (size_t)id * 128) + lane);
            ax += v.x; ay += v.y;
        }
        *((float2*)(m1 + (size_t)w * 128) + lane) = make_float2(ax * 0.1f, ay * 0.1f);
    } else if (w < 26624) {
        int row = w - 25600;
        const int* ip = ids1 + row * 25;
        float ax = 0.f, ay = 0.f;
#pragma unroll
        for (int t = 0; t < 25; ++t) {
            int id = ip[t];
            float2 v = *((const float2*)(feats + (size_t)id * 128) + lane);
            ax += v.x; ay += v.y;
        }
        const float s = 1.0f / 25.0f;
        *((float2*)(m0 + (size_t)row * 128) + lane) = make_float2(ax * s, ay * s);
    }
}

// Layer-1 via split-bf16 MFMA. Block: 256 thr, 64(M)x64(N) tile, K=128.
// z: 0 big-x (gather ids1), 1 big-n (m1), 2 small-x (gather ids0), 3 small-n (m0).
__launch_bounds__(256)
__global__ void gemm_l1_mfma(const float* __restrict__ feats,
                             const int* __restrict__ ids0, const int* __restrict__ ids1,
                             const float* __restrict__ m1, const float* __restrict__ m0,
                             const uint16_t* __restrict__ xh, const uint16_t* __restrict__ xl,
                             const uint16_t* __restrict__ nh, const uint16_t* __restrict__ nl,
                             float* __restrict__ h11, float* __restrict__ h10)
{
    const float* A; const int* g; const uint16_t* WH; const uint16_t* WL;
    float* C; int rows, ccol0;
    switch (blockIdx.z) {
    case 0:  A = feats; g = ids1;    WH = xh; WL = xl; C = h11; rows = 25600; ccol0 = 0;   break;
    case 1:  A = m1;    g = nullptr; WH = nh; WL = nl; C = h11; rows = 25600; ccol0 = 128; break;
    case 2:  A = feats; g = ids0;    WH = xh; WL = xl; C = h10; rows = 1024;  ccol0 = 0;   break;
    default: A = m0;    g = nullptr; WH = nh; WL = nl; C = h10; rows = 1024;  ccol0 = 128; break;
    }
    const int rb = blockIdx.x * 64;
    if (rb >= rows) return;
    const int nb0 = blockIdx.y * 64;

    __shared__ __align__(16) uint16_t Ahi[64][136];
    __shared__ __align__(16) uint16_t Alo[64][136];
    __shared__ __align__(16) uint16_t Bhi[64][136];
    __shared__ __align__(16) uint16_t Blo[64][136];

    const int tid = threadIdx.x;

    // Stage A: 64 rows x 128 k f32 -> bf16 hi/lo. 2048 float4 slots.
#pragma unroll
    for (int i = 0; i < 8; ++i) {
        int s = tid + i * 256;
        int row = s >> 5, f4 = s & 31;
        int k0 = f4 * 4;
        size_t arow = g ? (size_t)g[rb + row] : (size_t)(rb + row);
        float4 v = *(const float4*)(A + arow * 128 + k0);
        uint16_t h0 = f32_to_bf16_rne(v.x), h1 = f32_to_bf16_rne(v.y);
        uint16_t h2 = f32_to_bf16_rne(v.z), h3 = f32_to_bf16_rne(v.w);
        ushort4 hv = make_ushort4(h0, h1, h2, h3);
        ushort4 lv = make_ushort4(f32_to_bf16_rne(v.x - bf16_to_f32(h0)),
                                  f32_to_bf16_rne(v.y - bf16_to_f32(h1)),
                                  f32_to_bf16_rne(v.z - bf16_to_f32(h2)),
                                  f32_to_bf16_rne(v.w - bf16_to_f32(h3)));
        *(ushort4*)&Ahi[row][k0] = hv;
        *(ushort4*)&Alo[row][k0] = lv;
    }
    // Stage B: Wt[n][k] bf16, tile n in [nb0, nb0+64), k 0..127. 1024 uint4 slots each.
#pragma unroll
    for (int i = 0; i < 4; ++i) {
        int s = tid + i * 256;
        int n = s >> 4, ko = (s & 15) * 8;
        *(uint4*)&Bhi[n][ko] = *(const uint4*)(WH + (size_t)(nb0 + n) * 128 + ko);
        *(uint4*)&Blo[n][ko] = *(const uint4*)(WL + (size_t)(nb0 + n) * 128 + ko);
    }
    __syncthreads();

    const int lane = tid & 63;
    const int wv = tid >> 6;
    const int wm = (wv >> 1) * 32, wn = (wv & 1) * 32;
    const int fr = lane & 15;
    const int kb = lane >> 4;

    f32x4v acc[2][2] = {};
#pragma unroll
    for (int ks = 0; ks < 4; ++ks) {
        const int kk = ks * 32 + kb * 8;
        bf16x8v aH[2], aL[2], bH[2], bL[2];
#pragma unroll
        for (int mi = 0; mi < 2; ++mi) {
            aH[mi] = *(const bf16x8v*)&Ahi[wm + mi * 16 + fr][kk];
            aL[mi] = *(const bf16x8v*)&Alo[wm + mi * 16 + fr][kk];
        }
#pragma unroll
        for (int ni = 0; ni < 2; ++ni) {
            bH[ni] = *(const bf16x8v*)&Bhi[wn + ni * 16 + fr][kk];
            bL[ni] = *(const bf16x8v*)&Blo[wn + ni * 16 + fr][kk];
        }
#pragma unroll
        for (int mi = 0; mi < 2; ++mi)
#pragma unroll
            for (int ni = 0; ni < 2; ++ni) {
                acc[mi][ni] = __builtin_amdgcn_mfma_f32_16x16x32_bf16(aH[mi], bH[ni], acc[mi][ni], 0, 0, 0);
                acc[mi][ni] = __builtin_amdgcn_mfma_f32_16x16x32_bf16(aH[mi], bL[ni], acc[mi][ni], 0, 0, 0);
                acc[mi][ni] = __builtin_amdgcn_mfma_f32_16x16x32_bf16(aL[mi], bH[ni], acc[mi][ni], 0, 0, 0);
            }
    }

    // C/D: col = lane&15, row = (lane>>4)*4 + reg. ReLU epilogue.
#pragma unroll
    for (int mi = 0; mi < 2; ++mi)
#pragma unroll
        for (int ni = 0; ni < 2; ++ni) {
            int orow = rb + wm + mi * 16 + kb * 4;
            int ocol = ccol0 + nb0 + wn + ni * 16 + fr;
#pragma unroll
            for (int r = 0; r < 4; ++r)
                C[(size_t)(orow + r) * 256 + ocol] = fmaxf(acc[mi][ni][r], 0.0f);
        }
}

// m2[row][0:256] = mean over 25 contiguous h11 rows. One wave per row.
__global__ void mean25_256_kernel(const float* __restrict__ in, float* __restrict__ out, int rows)
{
    int g = blockIdx.x * blockDim.x + threadIdx.x;
    int row = g >> 6, lane = g & 63;
    if (row >= rows) return;
    float a0 = 0, a1 = 0, a2 = 0, a3 = 0;
#pragma unroll
    for (int t = 0; t < 25; ++t) {
        float4 v = *((const float4*)(in + ((size_t)row * 25 + t) * 256) + lane);
        a0 += v.x; a1 += v.y; a2 += v.z; a3 += v.w;
    }
    const float s = 1.0f / 25.0f;
    float4 r; r.x = a0 * s; r.y = a1 * s; r.z = a2 * s; r.w = a3 * s;
    *((float4*)(out + (size_t)row * 256) + lane) = r;
}

// f32 tile GEMM for layer 2 (small: 1024 rows, K=256).
__device__ __forceinline__ void gemm_body(float (*As)[68], float (*Ws)[68],
    const float* __restrict__ A, int K,
    const float* __restrict__ W, int ldw, float* __restrict__ C, int ldc,
    int ccol0, int rows)
{
    const int tid = threadIdx.x;
    const int rb = blockIdx.x * 64;
    const int cb = blockIdx.y * 64;
    const int tx = tid & 15, ty = tid >> 4;
    float acc[4][4] = {};

    for (int k0 = 0; k0 < K; k0 += 64) {
#pragma unroll
        for (int i = 0; i < 4; ++i) {
            int idx = tid + i * 256;
            int r = idx >> 4, f = idx & 15;
            float4 v = *(const float4*)(A + (size_t)(rb + r) * K + k0 + f * 4);
            *(float4*)&As[r][f * 4] = v;
        }
#pragma unroll
        for (int i = 0; i < 4; ++i) {
            int idx = tid + i * 256;
            int kk = idx >> 4, f = idx & 15;
            float4 v = *(const float4*)(W + (size_t)(k0 + kk) * ldw + cb + f * 4);
            *(float4*)&Ws[kk][f * 4] = v;
        }
        __syncthreads();
#pragma unroll
        for (int kk = 0; kk < 64; ++kk) {
            float b[4];
            *(float4*)b = *(const float4*)&Ws[kk][tx * 4];
            float a[4];
#pragma unroll
            for (int i = 0; i < 4; ++i) a[i] = As[ty * 4 + i][kk];
#pragma unroll
            for (int i = 0; i < 4; ++i)
#pragma unroll
                for (int j = 0; j < 4; ++j)
                    acc[i][j] = fmaf(a[i], b[j], acc[i][j]);
        }
        __syncthreads();
    }
#pragma unroll
    for (int i = 0; i < 4; ++i) {
        int r = rb + ty * 4 + i;
        if (r >= rows) continue;
#pragma unroll
        for (int j = 0; j < 4; ++j)
            C[(size_t)r * ldc + ccol0 + cb + tx * 4 + j] = acc[i][j];
    }
}

__launch_bounds__(256)
__global__ void gemm_l2_kernel(const float* __restrict__ h10, const float* __restrict__ m2,
                               const float* __restrict__ Wx2, const float* __restrict__ Wn2,
                               float* __restrict__ h2)
{
    const float* A; const float* W; int ccol0;
    if (blockIdx.z == 0) { A = h10; W = Wx2; ccol0 = 0; }
    else                 { A = m2;  W = Wn2; ccol0 = 128; }
    __shared__ float As[64][68];
    __shared__ float Ws[64][68];
    gemm_body(As, Ws, A, 256, W, 128, h2, 256, ccol0, 1024);
}

// out[row][c] = normalize(H[row]) @ fc_w[:,c] + fc_b[c]. One wave per row.
__launch_bounds__(256)
__global__ void norm_fc_kernel(const float* __restrict__ H, const float* __restrict__ fcw,
                               const float* __restrict__ fcb, float* __restrict__ out, int rows)
{
    __shared__ float srow[4][256];
    int lane = threadIdx.x & 63;
    int w = threadIdx.x >> 6;
    int row = blockIdx.x * 4 + w;
    bool active = row < rows;

    float4 v = make_float4(0.f, 0.f, 0.f, 0.f);
    if (active) v = *((const float4*)(H + (size_t)row * 256) + lane);
    float ss = v.x * v.x + v.y * v.y + v.z * v.z + v.w * v.w;
#pragma unroll
    for (int o = 32; o > 0; o >>= 1) ss += __shfl_xor(ss, o, 64);
    float scale = 1.0f / fmaxf(sqrtf(ss), 1e-12f);
    float4 sv; sv.x = v.x * scale; sv.y = v.y * scale; sv.z = v.z * scale; sv.w = v.w * scale;
    *((float4*)&srow[w][0] + lane) = sv;
    __syncthreads();

    float acc = fcb[lane];
#pragma unroll 4
    for (int k = 0; k < 256; ++k)
        acc = fmaf(srow[w][k], fcw[(size_t)k * 64 + lane], acc);
    if (active) out[(size_t)row * 64 + lane] = acc;
}

extern "C" void kernel_launch(void* const* d_in, const int* in_sizes, int n_in,
                              void* d_out, int out_size, void* d_ws, size_t ws_size,
                              hipStream_t stream)
{
    const int*   ids   = (const int*)d_in[0];
    const float* feats = (const float*)d_in[1];
    const int*   adj   = (const int*)d_in[2];
    const float* W_x1  = (const float*)d_in[3];
    const float* W_n1  = (const float*)d_in[4];
    const float* W_x2  = (const float*)d_in[5];
    const float* W_n2  = (const float*)d_in[6];
    const float* fc_w  = (const float*)d_in[7];
    const float* fc_b  = (const float*)d_in[8];
    float* out = (float*)d_out;

    char* ws = (char*)d_ws;
    int*      ids1 = (int*)(ws + 0);            // 25600 ints           (102,400 B)
    float*    m1   = (float*)(ws + 102400);     // 25600 x 128 f32
    float*    m0   = (float*)(ws + 13209600);   // 1024 x 128
    float*    h11  = (float*)(ws + 13733888);   // 25600 x 256
    float*    h10  = (float*)(ws + 39948288);   // 1024 x 256
    float*    m2   = (float*)(ws + 40996864);   // 1024 x 256
    float*    h2   = (float*)(ws + 42045440);   // 1024 x 256
    uint16_t* xh   = (uint16_t*)(ws + 43094016);// 128x128 bf16 (32 KB each)
    uint16_t* xl   = (uint16_t*)(ws + 43126784);
    uint16_t* nh   = (uint16_t*)(ws + 43159552);
    uint16_t* nl   = (uint16_t*)(ws + 43192320);// end 43,225,088 B

    // JAX PRNG key derivation (threefry2x32, partitionable foldlike):
    uint32_t f0a, f0b, f1a, f1b, s0a, s0b, s1a, s1b;
    tf2x32(0u, 42u, 0u, 0u, f0a, f0b);
    tf2x32(0u, 42u, 0u, 1u, f1a, f1b);
    tf2x32(f0a, f0b, 0u, 1u, s0a, s0b);
    tf2x32(f1a, f1b, 0u, 1u, s1a, s1b);

    // 1) W split prep (tiny)
    wprep_kernel<<<dim3(64, 2), 256, 0, stream>>>(W_x1, W_n1, xh, xl, nh, nl);
    // 2) hop-1 sampling
    sample25_kernel<<<100, 256, 0, stream>>>(ids, adj, s0a, s0b, ids1, 25600);
    // 3) hop-2 sampling fused with feats means (m1), plus m0
    means_kernel<<<6656, 256, 0, stream>>>(ids1, adj, feats, s1a, s1b, m1, m0);
    // 4) layer 1: all four matmuls via split-bf16 MFMA, relu
    gemm_l1_mfma<<<dim3(400, 2, 4), 256, 0, stream>>>(feats, ids, ids1, m1, m0,
                                                      xh, xl, nh, nl, h11, h10);
    // 5) mean over 25 h11 rows
    mean25_256_kernel<<<256, 256, 0, stream>>>(h11, m2, 1024);
    // 6) layer 2: both matmuls, no act
    gemm_l2_kernel<<<dim3(16, 2, 2), 256, 0, stream>>>(h10, m2, W_x2, W_n2, h2);
    // 7) normalize rows + FC
    norm_fc_kernel<<<256, 256, 0, stream>>>(h2, fc_w, fc_b, out, 1024);
}

// Round 4
// 76.221 us; speedup vs baseline: 1.9706x; 1.2444x over previous
//
#include <hip/hip_runtime.h>
#include <stdint.h>
#include <stddef.h>

// ---------------------------------------------------------------------------
// GraphSAGE supervised forward (B=1024, D=HID=128, fanout 25/10, classes 64)
// Round 4: h11 never materialized (mean25 fused into MFMA epilogue via
// atomics); prep fused (wprep+sample25+zero-m2); tail fused (L2+norm+FC).
// 4 kernel launches total.
// ---------------------------------------------------------------------------

typedef short bf16x8v __attribute__((ext_vector_type(8)));
typedef float f32x4v __attribute__((ext_vector_type(4)));

__host__ __device__ inline void tf2x32(uint32_t k0, uint32_t k1,
                                       uint32_t x0, uint32_t x1,
                                       uint32_t &o0, uint32_t &o1)
{
    uint32_t ks2 = k0 ^ k1 ^ 0x1BD11BDAu;
    uint32_t v0 = x0 + k0, v1 = x1 + k1;
#define TFR(d) { v0 += v1; v1 = (v1 << (d)) | (v1 >> (32 - (d))); v1 ^= v0; }
    TFR(13) TFR(15) TFR(26) TFR(6)   v0 += k1;  v1 += ks2 + 1u;
    TFR(17) TFR(29) TFR(16) TFR(24)  v0 += ks2; v1 += k0 + 2u;
    TFR(13) TFR(15) TFR(26) TFR(6)   v0 += k0;  v1 += k1 + 3u;
    TFR(17) TFR(29) TFR(16) TFR(24)  v0 += k1;  v1 += ks2 + 4u;
    TFR(13) TFR(15) TFR(26) TFR(6)   v0 += ks2; v1 += k0 + 5u;
#undef TFR
    o0 = v0; o1 = v1;
}

__device__ inline uint16_t f32_to_bf16_rne(float f)
{
    uint32_t u = __float_as_uint(f);
    u += 0x7FFFu + ((u >> 16) & 1u);
    return (uint16_t)(u >> 16);
}
__device__ inline float bf16_to_f32(uint16_t h)
{
    return __uint_as_float(((uint32_t)h) << 16);
}

// prep: [0,32768) W split-transpose; [32768,58368) hop-1 sampling; rest zero m2.
__global__ void prep_kernel(const float* __restrict__ Wx1, const float* __restrict__ Wn1,
                            uint16_t* __restrict__ xh, uint16_t* __restrict__ xl,
                            uint16_t* __restrict__ nh, uint16_t* __restrict__ nl,
                            const int* __restrict__ ids, const int* __restrict__ adj,
                            uint32_t ka, uint32_t kb, int* __restrict__ ids1,
                            float4* __restrict__ m2z)
{
    int t = blockIdx.x * 256 + threadIdx.x;
    if (t < 32768) {
        int k = (t & 16383) >> 7, n = t & 127;
        const float* W = (t < 16384) ? Wx1 : Wn1;
        uint16_t* H = (t < 16384) ? xh : nh;
        uint16_t* L = (t < 16384) ? xl : nl;
        float v = W[k * 128 + n];
        uint16_t h = f32_to_bf16_rne(v);
        uint16_t l = f32_to_bf16_rne(v - bf16_to_f32(h));
        H[n * 128 + k] = h;
        L[n * 128 + k] = l;
    } else if (t < 58368) {
        int j = t - 32768;
        uint32_t h, l;
        tf2x32(ka, kb, 0u, (uint32_t)j, h, l);
        int s = ids[j / 25];
        ids1[j] = adj[(size_t)s * 128u + ((h ^ l) & 127u)];
    } else if (t < 123904) {
        m2z[t - 58368] = make_float4(0.f, 0.f, 0.f, 0.f);
    }
}

// One wave per output row.
//   waves [0, 25600): hop-2 sample (in-wave threefry) + mean of 10 feats -> m1
//   waves [25600, 26624): mean of 25 feats rows per ids1 -> m0
__global__ void means_kernel(const int* __restrict__ ids1, const int* __restrict__ adj,
                             const float* __restrict__ feats, uint32_t ka, uint32_t kb,
                             float* __restrict__ m1, float* __restrict__ m0)
{
    int g = blockIdx.x * blockDim.x + threadIdx.x;
    int w = g >> 6, lane = g & 63;
    if (w < 25600) {
        int s = ids1[w];
        int idv = 0;
        if (lane < 10) {
            uint32_t h, l;
            tf2x32(ka, kb, 0u, (uint32_t)(w * 10 + lane), h, l);
            idv = adj[(size_t)s * 128u + ((h ^ l) & 127u)];
        }
        float ax = 0.f, ay = 0.f;
#pragma unroll
        for (int t = 0; t < 10; ++t) {
            int id = __shfl(idv, t, 64);
            float2 v = *((const float2*)(feats + (size_t)id * 128) + lane);
            ax += v.x; ay += v.y;
        }
        *((float2*)(m1 + (size_t)w * 128) + lane) = make_float2(ax * 0.1f, ay * 0.1f);
    } else if (w < 26624) {
        int row = w - 25600;
        const int* ip = ids1 + row * 25;
        float ax = 0.f, ay = 0.f;
#pragma unroll
        for (int t = 0; t < 25; ++t) {
            int id = ip[t];
            float2 v = *((const float2*)(feats + (size_t)id * 128) + lane);
            ax += v.x; ay += v.y;
        }
        const float s = 1.0f / 25.0f;
        *((float2*)(m0 + (size_t)row * 128) + lane) = make_float2(ax * s, ay * s);
    }
}

// Layer-1 split-bf16 MFMA. 64x64 tile, K=128. z: 0 big-x, 1 big-n, 2 small-x, 3 small-n.
// z<2: fused 25-row mean epilogue -> atomicAdd into m2 (h11 never materialized).
// z>=2: normal relu write to h10.
__launch_bounds__(256)
__global__ void gemm_l1_mfma(const float* __restrict__ feats,
                             const int* __restrict__ ids0, const int* __restrict__ ids1,
                             const float* __restrict__ m1, const float* __restrict__ m0,
                             const uint16_t* __restrict__ xh, const uint16_t* __restrict__ xl,
                             const uint16_t* __restrict__ nh, const uint16_t* __restrict__ nl,
                             float* __restrict__ m2, float* __restrict__ h10)
{
    const float* A; const int* g; const uint16_t* WH; const uint16_t* WL;
    int rows, ccol0;
    switch (blockIdx.z) {
    case 0:  A = feats; g = ids1;    WH = xh; WL = xl; rows = 25600; ccol0 = 0;   break;
    case 1:  A = m1;    g = nullptr; WH = nh; WL = nl; rows = 25600; ccol0 = 128; break;
    case 2:  A = feats; g = ids0;    WH = xh; WL = xl; rows = 1024;  ccol0 = 0;   break;
    default: A = m0;    g = nullptr; WH = nh; WL = nl; rows = 1024;  ccol0 = 128; break;
    }
    const int rb = blockIdx.x * 64;
    if (rb >= rows) return;
    const int nb0 = blockIdx.y * 64;

    __shared__ __align__(16) char smem[69632];
    uint16_t (*Ahi)[136] = reinterpret_cast<uint16_t(*)[136]>(smem);
    uint16_t (*Alo)[136] = reinterpret_cast<uint16_t(*)[136]>(smem + 17408);
    uint16_t (*Bhi)[136] = reinterpret_cast<uint16_t(*)[136]>(smem + 34816);
    uint16_t (*Blo)[136] = reinterpret_cast<uint16_t(*)[136]>(smem + 52224);

    const int tid = threadIdx.x;

    // Stage A: 64 rows x 128 k f32 -> bf16 hi/lo.
#pragma unroll
    for (int i = 0; i < 8; ++i) {
        int s = tid + i * 256;
        int row = s >> 5, f4 = s & 31;
        int k0 = f4 * 4;
        size_t arow = g ? (size_t)g[rb + row] : (size_t)(rb + row);
        float4 v = *(const float4*)(A + arow * 128 + k0);
        uint16_t h0 = f32_to_bf16_rne(v.x), h1 = f32_to_bf16_rne(v.y);
        uint16_t h2 = f32_to_bf16_rne(v.z), h3 = f32_to_bf16_rne(v.w);
        ushort4 hv = make_ushort4(h0, h1, h2, h3);
        ushort4 lv = make_ushort4(f32_to_bf16_rne(v.x - bf16_to_f32(h0)),
                                  f32_to_bf16_rne(v.y - bf16_to_f32(h1)),
                                  f32_to_bf16_rne(v.z - bf16_to_f32(h2)),
                                  f32_to_bf16_rne(v.w - bf16_to_f32(h3)));
        *(ushort4*)&Ahi[row][k0] = hv;
        *(ushort4*)&Alo[row][k0] = lv;
    }
    // Stage B: Wt[n][k] bf16 hi/lo, n in [nb0, nb0+64).
#pragma unroll
    for (int i = 0; i < 4; ++i) {
        int s = tid + i * 256;
        int n = s >> 4, ko = (s & 15) * 8;
        *(uint4*)&Bhi[n][ko] = *(const uint4*)(WH + (size_t)(nb0 + n) * 128 + ko);
        *(uint4*)&Blo[n][ko] = *(const uint4*)(WL + (size_t)(nb0 + n) * 128 + ko);
    }
    __syncthreads();

    const int lane = tid & 63;
    const int wv = tid >> 6;
    const int wm = (wv >> 1) * 32, wn = (wv & 1) * 32;
    const int fr = lane & 15;
    const int kb = lane >> 4;

    f32x4v acc[2][2] = {};
#pragma unroll
    for (int ks = 0; ks < 4; ++ks) {
        const int kk = ks * 32 + kb * 8;
        bf16x8v aH[2], aL[2], bH[2], bL[2];
#pragma unroll
        for (int mi = 0; mi < 2; ++mi) {
            aH[mi] = *(const bf16x8v*)&Ahi[wm + mi * 16 + fr][kk];
            aL[mi] = *(const bf16x8v*)&Alo[wm + mi * 16 + fr][kk];
        }
#pragma unroll
        for (int ni = 0; ni < 2; ++ni) {
            bH[ni] = *(const bf16x8v*)&Bhi[wn + ni * 16 + fr][kk];
            bL[ni] = *(const bf16x8v*)&Blo[wn + ni * 16 + fr][kk];
        }
#pragma unroll
        for (int mi = 0; mi < 2; ++mi)
#pragma unroll
            for (int ni = 0; ni < 2; ++ni) {
                acc[mi][ni] = __builtin_amdgcn_mfma_f32_16x16x32_bf16(aH[mi], bH[ni], acc[mi][ni], 0, 0, 0);
                acc[mi][ni] = __builtin_amdgcn_mfma_f32_16x16x32_bf16(aH[mi], bL[ni], acc[mi][ni], 0, 0, 0);
                acc[mi][ni] = __builtin_amdgcn_mfma_f32_16x16x32_bf16(aL[mi], bH[ni], acc[mi][ni], 0, 0, 0);
            }
    }

    // C/D layout: col = lane&15 (fr), row = kb*4 + reg.
    if (blockIdx.z < 2) {
        // Fused mean25: relu tile -> LDS (reuse A region), group-reduce, atomicAdd m2.
        __syncthreads();
        float (*Red)[68] = reinterpret_cast<float(*)[68]>(smem);   // 64x68x4 = 17408 B
#pragma unroll
        for (int mi = 0; mi < 2; ++mi)
#pragma unroll
            for (int ni = 0; ni < 2; ++ni) {
                int rl = wm + mi * 16 + kb * 4;
                int cl = wn + ni * 16 + fr;
#pragma unroll
                for (int r = 0; r < 4; ++r)
                    Red[rl + r][cl] = fmaxf(acc[mi][ni][r], 0.0f);
            }
        __syncthreads();
        int col = tid & 63, gs = tid >> 6;
        int gg = rb / 25 + gs;
        int rs = max(gg * 25, rb), re = min(gg * 25 + 25, rb + 64);
        if (rs < re) {
            float s = 0.f;
            for (int r = rs; r < re; ++r) s += Red[r - rb][col];
            atomicAdd(&m2[(size_t)gg * 256 + ccol0 + nb0 + col], s * (1.0f / 25.0f));
        }
    } else {
#pragma unroll
        for (int mi = 0; mi < 2; ++mi)
#pragma unroll
            for (int ni = 0; ni < 2; ++ni) {
                int orow = rb + wm + mi * 16 + kb * 4;
                int ocol = ccol0 + nb0 + wn + ni * 16 + fr;
#pragma unroll
                for (int r = 0; r < 4; ++r)
                    h10[(size_t)(orow + r) * 256 + ocol] = fmaxf(acc[mi][ni][r], 0.0f);
            }
    }
}

// Tail: layer-2 GEMM (K=256) + row-normalize + FC. 4 rows/block, 256 blocks.
// wave w owns row w throughout.
__launch_bounds__(256)
__global__ void tail_kernel(const float* __restrict__ h10, const float* __restrict__ m2,
                            const float* __restrict__ Wx2, const float* __restrict__ Wn2,
                            const float* __restrict__ fcw, const float* __restrict__ fcb,
                            float* __restrict__ out)
{
    __shared__ float X[4][260];
    __shared__ float M[4][260];
    __shared__ float H[4][260];
    const int tid = threadIdx.x;
    const int r0 = blockIdx.x * 4;

    // load 4 h10 rows + 4 m2 rows (256 float4 each, 1 per thread)
    {
        int r = tid >> 6, q = tid & 63;
        *(float4*)&X[r][q * 4] = *((const float4*)(h10 + (size_t)(r0 + r) * 256) + q);
        *(float4*)&M[r][q * 4] = *((const float4*)(m2 + (size_t)(r0 + r) * 256) + q);
    }
    __syncthreads();

    // layer-2: H[r][tid] ; col<128 -> X@Wx2, else M@Wn2
    {
        const float* W = (tid < 128) ? Wx2 : Wn2;
        const float (*S)[260] = (tid < 128) ? X : M;
        int c = tid & 127;
        float acc0 = 0.f, acc1 = 0.f, acc2 = 0.f, acc3 = 0.f;
        for (int k4 = 0; k4 < 256; k4 += 4) {
            float4 s0 = *(const float4*)&S[0][k4];
            float4 s1 = *(const float4*)&S[1][k4];
            float4 s2 = *(const float4*)&S[2][k4];
            float4 s3 = *(const float4*)&S[3][k4];
            float w0 = W[(size_t)(k4 + 0) * 128 + c];
            float w1 = W[(size_t)(k4 + 1) * 128 + c];
            float w2 = W[(size_t)(k4 + 2) * 128 + c];
            float w3 = W[(size_t)(k4 + 3) * 128 + c];
            acc0 = fmaf(s0.x, w0, fmaf(s0.y, w1, fmaf(s0.z, w2, fmaf(s0.w, w3, acc0))));
            acc1 = fmaf(s1.x, w0, fmaf(s1.y, w1, fmaf(s1.z, w2, fmaf(s1.w, w3, acc1))));
            acc2 = fmaf(s2.x, w0, fmaf(s2.y, w1, fmaf(s2.z, w2, fmaf(s2.w, w3, acc2))));
            acc3 = fmaf(s3.x, w0, fmaf(s3.y, w1, fmaf(s3.z, w2, fmaf(s3.w, w3, acc3))));
        }
        H[0][tid] = acc0; H[1][tid] = acc1; H[2][tid] = acc2; H[3][tid] = acc3;
    }
    __syncthreads();

    // normalize row w (wave w) + FC
    const int w = tid >> 6, lane = tid & 63;
    float4 hv = *((const float4*)&H[w][0] + lane);
    float ss = hv.x * hv.x + hv.y * hv.y + hv.z * hv.z + hv.w * hv.w;
#pragma unroll
    for (int o = 32; o > 0; o >>= 1) ss += __shfl_xor(ss, o, 64);
    float scale = 1.0f / fmaxf(sqrtf(ss), 1e-12f);

    float acc = 0.f;
    for (int k4 = 0; k4 < 256; k4 += 4) {
        float4 h4 = *(const float4*)&H[w][k4];
        acc = fmaf(h4.x, fcw[(size_t)(k4 + 0) * 64 + lane],
              fmaf(h4.y, fcw[(size_t)(k4 + 1) * 64 + lane],
              fmaf(h4.z, fcw[(size_t)(k4 + 2) * 64 + lane],
              fmaf(h4.w, fcw[(size_t)(k4 + 3) * 64 + lane], acc))));
    }
    out[(size_t)(r0 + w) * 64 + lane] = acc * scale + fcb[lane];
}

extern "C" void kernel_launch(void* const* d_in, const int* in_sizes, int n_in,
                              void* d_out, int out_size, void* d_ws, size_t ws_size,
                              hipStream_t stream)
{
    const int*   ids   = (const int*)d_in[0];
    const float* feats = (const float*)d_in[1];
    const int*   adj   = (const int*)d_in[2];
    const float* W_x1  = (const float*)d_in[3];
    const float* W_n1  = (const float*)d_in[4];
    const float* W_x2  = (const float*)d_in[5];
    const float* W_n2  = (const float*)d_in[6];
    const float* fc_w  = (const float*)d_in[7];
    const float* fc_b  = (const float*)d_in[8];
    float* out = (float*)d_out;

    char* ws = (char*)d_ws;
    int*      ids1 = (int*)(ws + 0);            // 25600 ints
    float*    m1   = (float*)(ws + 102400);     // 25600 x 128 f32
    float*    m0   = (float*)(ws + 13209600);   // 1024 x 128
    float*    h10  = (float*)(ws + 39948288);   // 1024 x 256
    float*    m2   = (float*)(ws + 40996864);   // 1024 x 256 (atomic accum)
    uint16_t* xh   = (uint16_t*)(ws + 43094016);// 128x128 bf16 each
    uint16_t* xl   = (uint16_t*)(ws + 43126784);
    uint16_t* nh   = (uint16_t*)(ws + 43159552);
    uint16_t* nl   = (uint16_t*)(ws + 43192320);

    // JAX PRNG key derivation (threefry2x32, partitionable foldlike):
    uint32_t f0a, f0b, f1a, f1b, s0a, s0b, s1a, s1b;
    tf2x32(0u, 42u, 0u, 0u, f0a, f0b);
    tf2x32(0u, 42u, 0u, 1u, f1a, f1b);
    tf2x32(f0a, f0b, 0u, 1u, s0a, s0b);
    tf2x32(f1a, f1b, 0u, 1u, s1a, s1b);

    // 1) prep: W splits + hop-1 sampling + zero m2
    prep_kernel<<<484, 256, 0, stream>>>(W_x1, W_n1, xh, xl, nh, nl,
                                         ids, adj, s0a, s0b, ids1, (float4*)m2);
    // 2) hop-2 sampling fused with feats means (m1), plus m0
    means_kernel<<<6656, 256, 0, stream>>>(ids1, adj, feats, s1a, s1b, m1, m0);
    // 3) layer 1: four matmuls via split-bf16 MFMA; big path feeds m2 directly
    gemm_l1_mfma<<<dim3(400, 2, 4), 256, 0, stream>>>(feats, ids, ids1, m1, m0,
                                                      xh, xl, nh, nl, m2, h10);
    // 4) tail: layer-2 GEMM + normalize + FC
    tail_kernel<<<256, 256, 0, stream>>>(h10, m2, W_x2, W_n2, fc_w, fc_b, out);
}

// Round 7
// 70.287 us; speedup vs baseline: 2.1369x; 1.0844x over previous
//
#include <hip/hip_runtime.h>
#include <stdint.h>
#include <stddef.h>

// ---------------------------------------------------------------------------
// GraphSAGE supervised forward (B=1024, D=HID=128, fanout 25/10, classes 64)
// Round 7: recovery to validated r4 structure; prep fused into means kernel
// (inline hop-1 threefry). 3 launches: means_prep -> gemm_l1 -> tail.
// NOTE: cooperative launch is incompatible with harness graph capture (r5/r6).
// ---------------------------------------------------------------------------

typedef short bf16x8v __attribute__((ext_vector_type(8)));
typedef float f32x4v __attribute__((ext_vector_type(4)));

__host__ __device__ inline void tf2x32(uint32_t k0, uint32_t k1,
                                       uint32_t x0, uint32_t x1,
                                       uint32_t &o0, uint32_t &o1)
{
    uint32_t ks2 = k0 ^ k1 ^ 0x1BD11BDAu;
    uint32_t v0 = x0 + k0, v1 = x1 + k1;
#define TFR(d) { v0 += v1; v1 = (v1 << (d)) | (v1 >> (32 - (d))); v1 ^= v0; }
    TFR(13) TFR(15) TFR(26) TFR(6)   v0 += k1;  v1 += ks2 + 1u;
    TFR(17) TFR(29) TFR(16) TFR(24)  v0 += ks2; v1 += k0 + 2u;
    TFR(13) TFR(15) TFR(26) TFR(6)   v0 += k0;  v1 += k1 + 3u;
    TFR(17) TFR(29) TFR(16) TFR(24)  v0 += k1;  v1 += ks2 + 4u;
    TFR(13) TFR(15) TFR(26) TFR(6)   v0 += ks2; v1 += k0 + 5u;
#undef TFR
    o0 = v0; o1 = v1;
}

__device__ inline uint16_t f32_to_bf16_rne(float f)
{
    uint32_t u = __float_as_uint(f);
    u += 0x7FFFu + ((u >> 16) & 1u);
    return (uint16_t)(u >> 16);
}
__device__ inline float bf16_to_f32(uint16_t h)
{
    return __uint_as_float(((uint32_t)h) << 16);
}

// Fused prep + means. Grid 6656x256 (= 26624 waves).
//   bid<384 prefix (1 item/thread): t<32768 W split-transpose; else zero m2.
//   waves [0, 25600): inline hop-1 (write ids1[w]) + hop-2 sample + mean10 -> m1
//   waves [25600, 26624): inline hop-1 x25 + mean25(feats) -> m0
__global__ void means_prep_kernel(const int* __restrict__ ids, const int* __restrict__ adj,
                                  const float* __restrict__ feats,
                                  const float* __restrict__ Wx1, const float* __restrict__ Wn1,
                                  uint16_t* __restrict__ xh, uint16_t* __restrict__ xl,
                                  uint16_t* __restrict__ nh, uint16_t* __restrict__ nl,
                                  uint32_t s0a, uint32_t s0b, uint32_t s1a, uint32_t s1b,
                                  int* __restrict__ ids1, float* __restrict__ m1,
                                  float* __restrict__ m0, float4* __restrict__ m2z)
{
    const int tid = threadIdx.x;
    const int bid = blockIdx.x;

    if (bid < 384) {                        // prep prefix: one item per thread
        int t = bid * 256 + tid;            // [0, 98304)
        if (t < 32768) {
            int k = (t & 16383) >> 7, n = t & 127;
            const float* W = (t < 16384) ? Wx1 : Wn1;
            uint16_t* H = (t < 16384) ? xh : nh;
            uint16_t* L = (t < 16384) ? xl : nl;
            float v = W[k * 128 + n];
            uint16_t h = f32_to_bf16_rne(v);
            uint16_t l = f32_to_bf16_rne(v - bf16_to_f32(h));
            H[n * 128 + k] = h;
            L[n * 128 + k] = l;
        } else {
            m2z[t - 32768] = make_float4(0.f, 0.f, 0.f, 0.f);   // 65536 float4
        }
    }

    const int w = (bid * 256 + tid) >> 6;
    const int lane = tid & 63;
    if (w < 25600) {
        // inline hop-1 for this neighbor slot (all lanes compute the same value)
        uint32_t h0, l0;
        tf2x32(s0a, s0b, 0u, (uint32_t)w, h0, l0);
        int s1idx = adj[(size_t)ids[w / 25] * 128u + ((h0 ^ l0) & 127u)];
        if (lane == 0) ids1[w] = s1idx;     // for the GEMM gather
        // hop-2 sample (lanes 0-9) + mean of 10 feature rows
        int idv = 0;
        if (lane < 10) {
            uint32_t h, l;
            tf2x32(s1a, s1b, 0u, (uint32_t)(w * 10 + lane), h, l);
            idv = adj[(size_t)s1idx * 128u + ((h ^ l) & 127u)];
        }
        float ax = 0.f, ay = 0.f;
#pragma unroll
        for (int t = 0; t < 10; ++t) {
            int id = __shfl(idv, t, 64);
            float2 v = *((const float2*)(feats + (size_t)id * 128) + lane);
            ax += v.x; ay += v.y;
        }
        *((float2*)(m1 + (size_t)w * 128) + lane) = make_float2(ax * 0.1f, ay * 0.1f);
    } else if (w < 26624) {
        int row = w - 25600;
        int s = ids[row];
        int idv = 0;
        if (lane < 25) {
            uint32_t h, l;
            tf2x32(s0a, s0b, 0u, (uint32_t)(row * 25 + lane), h, l);
            idv = adj[(size_t)s * 128u + ((h ^ l) & 127u)];
        }
        float ax = 0.f, ay = 0.f;
#pragma unroll
        for (int t = 0; t < 25; ++t) {
            int id = __shfl(idv, t, 64);
            float2 v = *((const float2*)(feats + (size_t)id * 128) + lane);
            ax += v.x; ay += v.y;
        }
        const float sc = 1.0f / 25.0f;
        *((float2*)(m0 + (size_t)row * 128) + lane) = make_float2(ax * sc, ay * sc);
    }
}

// Layer-1 split-bf16 MFMA (validated r4 code). 64x64 tile, K=128.
// z: 0 big-x, 1 big-n, 2 small-x, 3 small-n.
// z<2: fused 25-row mean epilogue -> atomicAdd into m2. z>=2: relu write h10.
__launch_bounds__(256)
__global__ void gemm_l1_mfma(const float* __restrict__ feats,
                             const int* __restrict__ ids0, const int* __restrict__ ids1,
                             const float* __restrict__ m1, const float* __restrict__ m0,
                             const uint16_t* __restrict__ xh, const uint16_t* __restrict__ xl,
                             const uint16_t* __restrict__ nh, const uint16_t* __restrict__ nl,
                             float* __restrict__ m2, float* __restrict__ h10)
{
    const float* A; const int* g; const uint16_t* WH; const uint16_t* WL;
    int rows, ccol0;
    switch (blockIdx.z) {
    case 0:  A = feats; g = ids1;    WH = xh; WL = xl; rows = 25600; ccol0 = 0;   break;
    case 1:  A = m1;    g = nullptr; WH = nh; WL = nl; rows = 25600; ccol0 = 128; break;
    case 2:  A = feats; g = ids0;    WH = xh; WL = xl; rows = 1024;  ccol0 = 0;   break;
    default: A = m0;    g = nullptr; WH = nh; WL = nl; rows = 1024;  ccol0 = 128; break;
    }
    const int rb = blockIdx.x * 64;
    if (rb >= rows) return;
    const int nb0 = blockIdx.y * 64;

    __shared__ __align__(16) char smem[69632];
    uint16_t (*Ahi)[136] = reinterpret_cast<uint16_t(*)[136]>(smem);
    uint16_t (*Alo)[136] = reinterpret_cast<uint16_t(*)[136]>(smem + 17408);
    uint16_t (*Bhi)[136] = reinterpret_cast<uint16_t(*)[136]>(smem + 34816);
    uint16_t (*Blo)[136] = reinterpret_cast<uint16_t(*)[136]>(smem + 52224);

    const int tid = threadIdx.x;

    // Stage A: 64 rows x 128 k f32 -> bf16 hi/lo.
#pragma unroll
    for (int i = 0; i < 8; ++i) {
        int s = tid + i * 256;
        int row = s >> 5, f4 = s & 31;
        int k0 = f4 * 4;
        size_t arow = g ? (size_t)g[rb + row] : (size_t)(rb + row);
        float4 v = *(const float4*)(A + arow * 128 + k0);
        uint16_t h0 = f32_to_bf16_rne(v.x), h1 = f32_to_bf16_rne(v.y);
        uint16_t h2 = f32_to_bf16_rne(v.z), h3 = f32_to_bf16_rne(v.w);
        *(ushort4*)&Ahi[row][k0] = make_ushort4(h0, h1, h2, h3);
        *(ushort4*)&Alo[row][k0] = make_ushort4(f32_to_bf16_rne(v.x - bf16_to_f32(h0)),
                                                f32_to_bf16_rne(v.y - bf16_to_f32(h1)),
                                                f32_to_bf16_rne(v.z - bf16_to_f32(h2)),
                                                f32_to_bf16_rne(v.w - bf16_to_f32(h3)));
    }
    // Stage B: Wt[n][k] bf16 hi/lo, n in [nb0, nb0+64).
#pragma unroll
    for (int i = 0; i < 4; ++i) {
        int s = tid + i * 256;
        int n = s >> 4, ko = (s & 15) * 8;
        *(uint4*)&Bhi[n][ko] = *(const uint4*)(WH + (size_t)(nb0 + n) * 128 + ko);
        *(uint4*)&Blo[n][ko] = *(const uint4*)(WL + (size_t)(nb0 + n) * 128 + ko);
    }
    __syncthreads();

    const int lane = tid & 63;
    const int wv = tid >> 6;
    const int wm = (wv >> 1) * 32, wn = (wv & 1) * 32;
    const int fr = lane & 15;
    const int kb = lane >> 4;

    f32x4v acc[2][2] = {};
#pragma unroll
    for (int ks = 0; ks < 4; ++ks) {
        const int kk = ks * 32 + kb * 8;
        bf16x8v aH[2], aL[2], bH[2], bL[2];
#pragma unroll
        for (int mi = 0; mi < 2; ++mi) {
            aH[mi] = *(const bf16x8v*)&Ahi[wm + mi * 16 + fr][kk];
            aL[mi] = *(const bf16x8v*)&Alo[wm + mi * 16 + fr][kk];
        }
#pragma unroll
        for (int ni = 0; ni < 2; ++ni) {
            bH[ni] = *(const bf16x8v*)&Bhi[wn + ni * 16 + fr][kk];
            bL[ni] = *(const bf16x8v*)&Blo[wn + ni * 16 + fr][kk];
        }
#pragma unroll
        for (int mi = 0; mi < 2; ++mi)
#pragma unroll
            for (int ni = 0; ni < 2; ++ni) {
                acc[mi][ni] = __builtin_amdgcn_mfma_f32_16x16x32_bf16(aH[mi], bH[ni], acc[mi][ni], 0, 0, 0);
                acc[mi][ni] = __builtin_amdgcn_mfma_f32_16x16x32_bf16(aH[mi], bL[ni], acc[mi][ni], 0, 0, 0);
                acc[mi][ni] = __builtin_amdgcn_mfma_f32_16x16x32_bf16(aL[mi], bH[ni], acc[mi][ni], 0, 0, 0);
            }
    }

    // C/D layout: col = lane&15 (fr), row = kb*4 + reg.
    if (blockIdx.z < 2) {
        // Fused mean25: relu tile -> LDS (reuse A region), group-reduce, atomicAdd m2.
        __syncthreads();
        float (*Red)[68] = reinterpret_cast<float(*)[68]>(smem);
#pragma unroll
        for (int mi = 0; mi < 2; ++mi)
#pragma unroll
            for (int ni = 0; ni < 2; ++ni) {
                int rl = wm + mi * 16 + kb * 4;
                int cl = wn + ni * 16 + fr;
#pragma unroll
                for (int r = 0; r < 4; ++r)
                    Red[rl + r][cl] = fmaxf(acc[mi][ni][r], 0.0f);
            }
        __syncthreads();
        int col = tid & 63, gs = tid >> 6;
        int gg = rb / 25 + gs;
        int rs = max(gg * 25, rb), re = min(gg * 25 + 25, rb + 64);
        if (rs < re) {
            float s = 0.f;
            for (int r = rs; r < re; ++r) s += Red[r - rb][col];
            atomicAdd(&m2[(size_t)gg * 256 + ccol0 + nb0 + col], s * (1.0f / 25.0f));
        }
    } else {
#pragma unroll
        for (int mi = 0; mi < 2; ++mi)
#pragma unroll
            for (int ni = 0; ni < 2; ++ni) {
                int orow = rb + wm + mi * 16 + kb * 4;
                int ocol = ccol0 + nb0 + wn + ni * 16 + fr;
#pragma unroll
                for (int r = 0; r < 4; ++r)
                    h10[(size_t)(orow + r) * 256 + ocol] = fmaxf(acc[mi][ni][r], 0.0f);
            }
    }
}

// Tail: layer-2 GEMM (K=256) + row-normalize + FC (validated r4 code).
__launch_bounds__(256)
__global__ void tail_kernel(const float* __restrict__ h10, const float* __restrict__ m2,
                            const float* __restrict__ Wx2, const float* __restrict__ Wn2,
                            const float* __restrict__ fcw, const float* __restrict__ fcb,
                            float* __restrict__ out)
{
    __shared__ float X[4][260];
    __shared__ float M[4][260];
    __shared__ float H[4][260];
    const int tid = threadIdx.x;
    const int r0 = blockIdx.x * 4;

    {
        int r = tid >> 6, q = tid & 63;
        *(float4*)&X[r][q * 4] = *((const float4*)(h10 + (size_t)(r0 + r) * 256) + q);
        *(float4*)&M[r][q * 4] = *((const float4*)(m2 + (size_t)(r0 + r) * 256) + q);
    }
    __syncthreads();

    {
        const float* W = (tid < 128) ? Wx2 : Wn2;
        const float (*S)[260] = (tid < 128) ? X : M;
        int c = tid & 127;
        float acc0 = 0.f, acc1 = 0.f, acc2 = 0.f, acc3 = 0.f;
        for (int k4 = 0; k4 < 256; k4 += 4) {
            float4 s0 = *(const float4*)&S[0][k4];
            float4 s1 = *(const float4*)&S[1][k4];
            float4 s2 = *(const float4*)&S[2][k4];
            float4 s3 = *(const float4*)&S[3][k4];
            float w0 = W[(size_t)(k4 + 0) * 128 + c];
            float w1 = W[(size_t)(k4 + 1) * 128 + c];
            float w2 = W[(size_t)(k4 + 2) * 128 + c];
            float w3 = W[(size_t)(k4 + 3) * 128 + c];
            acc0 = fmaf(s0.x, w0, fmaf(s0.y, w1, fmaf(s0.z, w2, fmaf(s0.w, w3, acc0))));
            acc1 = fmaf(s1.x, w0, fmaf(s1.y, w1, fmaf(s1.z, w2, fmaf(s1.w, w3, acc1))));
            acc2 = fmaf(s2.x, w0, fmaf(s2.y, w1, fmaf(s2.z, w2, fmaf(s2.w, w3, acc2))));
            acc3 = fmaf(s3.x, w0, fmaf(s3.y, w1, fmaf(s3.z, w2, fmaf(s3.w, w3, acc3))));
        }
        H[0][tid] = acc0; H[1][tid] = acc1; H[2][tid] = acc2; H[3][tid] = acc3;
    }
    __syncthreads();

    const int w = tid >> 6, lane = tid & 63;
    float4 hv = *((const float4*)&H[w][0] + lane);
    float ss = hv.x * hv.x + hv.y * hv.y + hv.z * hv.z + hv.w * hv.w;
#pragma unroll
    for (int o = 32; o > 0; o >>= 1) ss += __shfl_xor(ss, o, 64);
    float scale = 1.0f / fmaxf(sqrtf(ss), 1e-12f);

    float acc = 0.f;
    for (int k4 = 0; k4 < 256; k4 += 4) {
        float4 h4 = *(const float4*)&H[w][k4];
        acc = fmaf(h4.x, fcw[(size_t)(k4 + 0) * 64 + lane],
              fmaf(h4.y, fcw[(size_t)(k4 + 1) * 64 + lane],
              fmaf(h4.z, fcw[(size_t)(k4 + 2) * 64 + lane],
              fmaf(h4.w, fcw[(size_t)(k4 + 3) * 64 + lane], acc))));
    }
    out[(size_t)(r0 + w) * 64 + lane] = acc * scale + fcb[lane];
}

extern "C" void kernel_launch(void* const* d_in, const int* in_sizes, int n_in,
                              void* d_out, int out_size, void* d_ws, size_t ws_size,
                              hipStream_t stream)
{
    const int*   ids   = (const int*)d_in[0];
    const float* feats = (const float*)d_in[1];
    const int*   adj   = (const int*)d_in[2];
    const float* W_x1  = (const float*)d_in[3];
    const float* W_n1  = (const float*)d_in[4];
    const float* W_x2  = (const float*)d_in[5];
    const float* W_n2  = (const float*)d_in[6];
    const float* fc_w  = (const float*)d_in[7];
    const float* fc_b  = (const float*)d_in[8];
    float* out = (float*)d_out;

    char* ws = (char*)d_ws;
    int*      ids1 = (int*)(ws + 0);            // 25600 ints
    float*    m1   = (float*)(ws + 102400);     // 25600 x 128 f32
    float*    m0   = (float*)(ws + 13209600);   // 1024 x 128
    float*    h10  = (float*)(ws + 39948288);   // 1024 x 256
    float*    m2   = (float*)(ws + 40996864);   // 1024 x 256 (atomic accum)
    uint16_t* xh   = (uint16_t*)(ws + 43094016);// 128x128 bf16 each
    uint16_t* xl   = (uint16_t*)(ws + 43126784);
    uint16_t* nh   = (uint16_t*)(ws + 43159552);
    uint16_t* nl   = (uint16_t*)(ws + 43192320);

    // JAX PRNG key derivation (threefry2x32, partitionable foldlike):
    uint32_t f0a, f0b, f1a, f1b, s0a, s0b, s1a, s1b;
    tf2x32(0u, 42u, 0u, 0u, f0a, f0b);
    tf2x32(0u, 42u, 0u, 1u, f1a, f1b);
    tf2x32(f0a, f0b, 0u, 1u, s0a, s0b);
    tf2x32(f1a, f1b, 0u, 1u, s1a, s1b);

    // 1) fused prep + means (inline hop-1; writes ids1, m1, m0; preps W, zeros m2)
    means_prep_kernel<<<6656, 256, 0, stream>>>(ids, adj, feats, W_x1, W_n1,
                                                xh, xl, nh, nl,
                                                s0a, s0b, s1a, s1b,
                                                ids1, m1, m0, (float4*)m2);
    // 2) layer 1: four matmuls via split-bf16 MFMA; big path feeds m2 directly
    gemm_l1_mfma<<<dim3(400, 2, 4), 256, 0, stream>>>(feats, ids, ids1, m1, m0,
                                                      xh, xl, nh, nl, m2, h10);
    // 3) tail: layer-2 GEMM + normalize + FC
    tail_kernel<<<256, 256, 0, stream>>>(h10, m2, W_x2, W_n2, fc_w, fc_b, out);
}